// Round 6
// baseline (325.382 us; speedup 1.0000x reference)
//
#include <hip/hip_runtime.h>
#include <stdint.h>

// Problem constants
#define B_   2
#define S_   2048      // SQ == SK
#define H_   1024
#define NH_  16
#define D_   64
#define KC_  3072      // KS*H = conv GEMM K-dim

typedef __attribute__((ext_vector_type(8))) short  short8;   // 8 x bf16 bits (4 VGPRs)
typedef __attribute__((ext_vector_type(4))) float  floatx4;  // MFMA C/D

typedef __attribute__((address_space(1))) const void gas_void;
typedef __attribute__((address_space(3))) void       las_void;

// async 16B global->LDS; LDS dest must be wave-uniform base + lane*16.
__device__ __forceinline__ void gld16(const void* g, void* l) {
    __builtin_amdgcn_global_load_lds((gas_void*)g, (las_void*)l, 16, 0, 0);
}

__device__ __forceinline__ unsigned short f2bf(float f) {
    union { float f; unsigned u; } v; v.f = f;
    unsigned r = v.u + 0x7fffu + ((v.u >> 16) & 1u);   // RNE
    return (unsigned short)(r >> 16);
}

// ---------------------------------------------------------------------------
// 1) Merged prep kernel (one launch instead of six).
//    pad: x [B,2048,1024] f32 -> xpad [B,2050,1024] bf16, zero rows 0 & 2049
//    (R5 BUG: batch decode was dropped -> batch 1 left poisoned. Restored.)
//    transpose: W [R][C] f32 -> Wt [C][R] bf16
// ---------------------------------------------------------------------------
__global__ __launch_bounds__(256) void k_prep(
    const float* __restrict__ qin, const float* __restrict__ sin,
    const float* __restrict__ Wq, const float* __restrict__ Wk,
    const float* __restrict__ Wv, const float* __restrict__ Wo,
    unsigned short* __restrict__ xqp, unsigned short* __restrict__ xsp,
    unsigned short* __restrict__ Wqt, unsigned short* __restrict__ Wkt,
    unsigned short* __restrict__ Wvt, unsigned short* __restrict__ Wot) {
    int bid = blockIdx.x, tid = threadIdx.x;
    if (bid < 8200) {
        // pad-convert: 4100 blocks per input, covering BOTH batches
        const float* src = (bid < 4100) ? qin : sin;
        unsigned short* dst = (bid < 4100) ? xqp : xsp;
        int b0 = (bid < 4100) ? bid : bid - 4100;
        int vid = (b0 * 256 + tid) * 4;
        if (vid >= B_ * 2050 * 1024) return;
        int row = vid >> 10;
        int b   = (row >= 2050) ? 1 : 0;
        int r   = row - b * 2050;
        int h   = vid & 1023;
        unsigned short o0 = 0, o1 = 0, o2 = 0, o3 = 0;
        if (r != 0 && r != 2049) {
            const float4 f = *(const float4*)(src + ((b * 2048 + r - 1) << 10) + h);
            o0 = f2bf(f.x); o1 = f2bf(f.y); o2 = f2bf(f.z); o3 = f2bf(f.w);
        }
        ushort4 o; o.x = o0; o.y = o1; o.z = o2; o.w = o3;
        *(ushort4*)(dst + vid) = o;
        return;
    }
    // transpose sections
    __shared__ float t[32][33];
    const float* src; unsigned short* dst; int R, bx, by;
    int tbid = bid - 8200;
    if (tbid < 9216) {                       // 3 big Ws: 3072 tiles each (32x96)
        int w = tbid / 3072, rem = tbid - w * 3072;
        src = (w == 0) ? Wq : (w == 1 ? Wk : Wv);
        dst = (w == 0) ? Wqt : (w == 1 ? Wkt : Wvt);
        R = 3072; bx = rem & 31; by = rem >> 5;
    } else {                                 // Wo: 1024 tiles (32x32)
        int rem = tbid - 9216;
        src = Wo; dst = Wot; R = 1024; bx = rem & 31; by = rem >> 5;
    }
    const int C = 1024;
    int c0 = bx * 32, r0 = by * 32;
    int tx = tid & 31, ty = tid >> 5;        // (32,8)
#pragma unroll
    for (int k = 0; k < 4; ++k)
        t[ty + k * 8][tx] = src[(long)(r0 + ty + k * 8) * C + c0 + tx];
    __syncthreads();
#pragma unroll
    for (int k = 0; k < 4; ++k)
        dst[(long)(c0 + ty + k * 8) * R + r0 + tx] = f2bf(t[tx][ty + k * 8]);
}

// ---------------------------------------------------------------------------
// 2) Conv-as-GEMM, shift-deduped, BK=32, 33 KB LDS -> all 768 blocks resident
//    (3 blocks/CU: zero dispatch tail, 3-way cross-block barrier overlap).
//    LDS layout: two 32-elem k-rows pair-packed into one 128 B line of eight
//    16 B slots, slot p = (((r&1)<<2)|kchunk) ^ ((r>>1)&7)  — same geometry
//    class as the proven conflict-free BK=64 swizzle (line index = row pair).
// ---------------------------------------------------------------------------
__global__ __launch_bounds__(256) void k_conv_gemm(
    const unsigned short* __restrict__ xq, const unsigned short* __restrict__ xs,
    const unsigned short* __restrict__ Wqt, const unsigned short* __restrict__ Wkt,
    const unsigned short* __restrict__ Wvt,
    const float* __restrict__ bq, const float* __restrict__ bk, const float* __restrict__ bv,
    unsigned short* __restrict__ Qo, unsigned short* __restrict__ Ko,
    unsigned short* __restrict__ Vo) {
    int z = blockIdx.z;
    const unsigned short* X = (z == 0) ? xq : xs;
    const unsigned short* W = (z == 0) ? Wqt : (z == 1 ? Wkt : Wvt);
    const float* bias = (z == 0) ? bq : (z == 1 ? bk : bv);

    __shared__ unsigned short Al[520 * 8];    // 130 rows x 32 k, pair-packed (8320 B)
    __shared__ unsigned short Bl[1536 * 8];   // 3 shifts x 128 rows x 32 k (24576 B)

    int n0 = blockIdx.x * 128, m0 = blockIdx.y * 128;
    int b = m0 >> 11;
    int tid = threadIdx.x, lane = tid & 63, w = tid >> 6;
    int quad = lane >> 4, l15 = lane & 15;
    int wm = w >> 1, wn = w & 1;

    floatx4 acc[4][4];
#pragma unroll
    for (int i = 0; i < 4; ++i)
#pragma unroll
        for (int j = 0; j < 4; ++j) acc[i][j] = (floatx4){0.f, 0.f, 0.f, 0.f};

    const unsigned short* Xbase = X + (m0 + 2 * b) * 1024;   // staged row r <-> xpad row m0+2b+r

    // staging: slot s -> (row r, kchunk c):  pr=s>>3, p=s&7, u=p^(pr&7), r=2pr+(u>>2), c=u&3
    int aoff[3];
#pragma unroll
    for (int it = 0; it < 3; ++it) {
        int s = it * 256 + tid;
        if (s < 520) {
            int pr = s >> 3, p = s & 7, u = p ^ (pr & 7);
            aoff[it] = (pr * 2 + (u >> 2)) * 1024 + (u & 3) * 8;
        }
    }
    int boff[6];
#pragma unroll
    for (int it = 0; it < 6; ++it) {
        int s = it * 256 + tid;
        int tt = s >> 9, sp = s & 511;
        int pr = sp >> 3, p = sp & 7, u = p ^ (pr & 7);
        boff[it] = (n0 + pr * 2 + (u >> 2)) * KC_ + tt * 1024 + (u & 3) * 8;
    }

    for (int kt = 0; kt < 32; ++kt) {
        int k0 = kt * 32;
        gld16(Xbase + aoff[0] + k0, (char*)Al + tid * 16);
        gld16(Xbase + aoff[1] + k0, (char*)Al + (256 + tid) * 16);
        if (tid < 8)
            gld16(Xbase + aoff[2] + k0, (char*)Al + (512 + tid) * 16);
#pragma unroll
        for (int it = 0; it < 6; ++it)
            gld16(W + boff[it] + k0, (char*)Bl + (it * 256 + tid) * 16);
        __syncthreads();

#pragma unroll
        for (int t = 0; t < 3; ++t) {
            short8 af[4], bf[4];
#pragma unroll
            for (int i = 0; i < 4; ++i) {
                int r  = wm * 64 + i * 16 + l15 + t;      // shifted A row
                int pr = r >> 1;
                int p  = (((r & 1) << 2) | quad) ^ (pr & 7);
                af[i]  = *(const short8*)(Al + (pr * 8 + p) * 8);
            }
#pragma unroll
            for (int j = 0; j < 4; ++j) {
                int n  = wn * 64 + j * 16 + l15;
                int pr = n >> 1;
                int p  = (((n & 1) << 2) | quad) ^ (pr & 7);
                bf[j]  = *(const short8*)(Bl + (t * 512 + pr * 8 + p) * 8);
            }
#pragma unroll
            for (int i = 0; i < 4; ++i)
#pragma unroll
                for (int j = 0; j < 4; ++j)
                    acc[i][j] = __builtin_amdgcn_mfma_f32_16x16x32_bf16(af[i], bf[j], acc[i][j], 0, 0, 0);
        }
        __syncthreads();
    }

    // epilogue: C/D layout col=lane&15, row=quad*4+reg
#pragma unroll
    for (int j = 0; j < 4; ++j) {
        int n = n0 + wn * 64 + j * 16 + l15;
        float bb = bias[n];
        int nh = n >> 6, d = n & 63;
#pragma unroll
        for (int i = 0; i < 4; ++i) {
            int srow = (m0 & 2047) + wm * 64 + i * 16 + quad * 4;
#pragma unroll
            for (int r = 0; r < 4; ++r) {
                float v = acc[i][j][r] + bb;
                int s = srow + r;
                if (z == 0)
                    Qo[((b * NH_ + nh) * 2048 + s) * 64 + d] = f2bf(v * 0.125f);
                else if (z == 1)
                    Ko[((b * NH_ + nh) * 2048 + s) * 64 + d] = f2bf(v);
                else
                    Vo[((b * NH_ + nh) * 64 + d) * 2048 + s] = f2bf(v);
            }
        }
    }
}

// ---------------------------------------------------------------------------
// 3) Flash attention (unchanged known-good).
// ---------------------------------------------------------------------------
__global__ __launch_bounds__(256) void k_flash(
    const unsigned short* __restrict__ Q, const unsigned short* __restrict__ K,
    const unsigned short* __restrict__ Vt, const float* __restrict__ mask,
    unsigned short* __restrict__ Ao) {
    __shared__ unsigned short Ul[128 * 136];   // 34816 B
    __shared__ unsigned short Vl[64 * 128];    // 16384 B

    int tid = threadIdx.x, w = tid >> 6, lane = tid & 63;
    int quad = lane >> 4, l15 = lane & 15;
    int bh = blockIdx.y;
    int b = bh >> 4, nh = bh & 15;
    int q0 = blockIdx.x * 128, wq = w * 32;

    short8 qf[2][2];
#pragma unroll
    for (int i = 0; i < 2; ++i)
#pragma unroll
        for (int kk = 0; kk < 2; ++kk)
            qf[i][kk] = *(const short8*)(Q + ((bh * 2048 + q0 + wq + i * 16 + l15) << 6) + kk * 32 + quad * 8);

    floatx4 oacc[2][4];
    float rsum[2][4];
#pragma unroll
    for (int i = 0; i < 2; ++i) {
#pragma unroll
        for (int j = 0; j < 4; ++j) oacc[i][j] = (floatx4){0.f, 0.f, 0.f, 0.f};
#pragma unroll
        for (int r = 0; r < 4; ++r) rsum[i][r] = 0.f;
    }
    const float* maskb = mask + b * S_;

    for (int kt = 0; kt < 16; ++kt) {
        int k0 = kt * 128;
#pragma unroll
        for (int it = 0; it < 4; ++it) {
            int e  = (it * 256 + tid) * 8;
            int kl = e >> 6;
            int c  = ((e >> 3) & 7) ^ (kl & 7);
            gld16(K + (bh * 2048 + k0 + kl) * 64 + c * 8, (char*)Ul + e * 2);
            int dl = e >> 7;
            int cp = (e >> 3) & 15;
            int c2 = (cp & 8) | ((cp ^ dl) & 7);
            gld16(Vt + (bh * 64 + dl) * 2048 + k0 + c2 * 8, (char*)Vl + e * 2);
        }
        __syncthreads();

        // S = Q K^T  (wave: 32 q-rows x 128 keys)
        floatx4 sacc[2][8];
#pragma unroll
        for (int i = 0; i < 2; ++i)
#pragma unroll
            for (int j = 0; j < 8; ++j) sacc[i][j] = (floatx4){0.f, 0.f, 0.f, 0.f};
#pragma unroll
        for (int j = 0; j < 8; ++j) {
            int kl = j * 16 + l15;
            int cp0 = (0 * 4 + quad) ^ (kl & 7);
            short8 bf0 = *(const short8*)(Ul + kl * 64 + cp0 * 8);
            int cp1 = (1 * 4 + quad) ^ (kl & 7);
            short8 bf1 = *(const short8*)(Ul + kl * 64 + cp1 * 8);
#pragma unroll
            for (int i = 0; i < 2; ++i) {
                sacc[i][j] = __builtin_amdgcn_mfma_f32_16x16x32_bf16(qf[i][0], bf0, sacc[i][j], 0, 0, 0);
                sacc[i][j] = __builtin_amdgcn_mfma_f32_16x16x32_bf16(qf[i][1], bf1, sacc[i][j], 0, 0, 0);
            }
        }
        __syncthreads();   // all waves done reading K-tile before P overwrites Ul

        // P = exp(S + mask*-1e9)
#pragma unroll
        for (int j = 0; j < 8; ++j) {
            float mv = maskb[k0 + j * 16 + l15] * (-1e9f);
#pragma unroll
            for (int i = 0; i < 2; ++i) {
                int row = wq + i * 16 + quad * 4;
#pragma unroll
                for (int r = 0; r < 4; ++r) {
                    float p = __expf(sacc[i][j][r] + mv);
                    rsum[i][r] += p;
                    Ul[(row + r) * 136 + j * 16 + l15] = f2bf(p);
                }
            }
        }
        // no barrier: each wave reads only its own P rows

        // O += P V
#pragma unroll
        for (int kk = 0; kk < 4; ++kk) {
            short8 af[2], bv4[4];
#pragma unroll
            for (int i = 0; i < 2; ++i)
                af[i] = *(const short8*)(Ul + (wq + i * 16 + l15) * 136 + kk * 32 + quad * 8);
#pragma unroll
            for (int j2 = 0; j2 < 4; ++j2) {
                int dl = j2 * 16 + l15;
                int c  = kk * 4 + quad;
                int cp = (c & 8) | ((c ^ dl) & 7);
                bv4[j2] = *(const short8*)(Vl + dl * 128 + cp * 8);
            }
#pragma unroll
            for (int i = 0; i < 2; ++i)
#pragma unroll
                for (int j2 = 0; j2 < 4; ++j2)
                    oacc[i][j2] = __builtin_amdgcn_mfma_f32_16x16x32_bf16(af[i], bv4[j2], oacc[i][j2], 0, 0, 0);
        }
        __syncthreads();
    }

#pragma unroll
    for (int i = 0; i < 2; ++i)
#pragma unroll
        for (int r = 0; r < 4; ++r) {
            float v = rsum[i][r];
            v += __shfl_xor(v, 1); v += __shfl_xor(v, 2);
            v += __shfl_xor(v, 4); v += __shfl_xor(v, 8);
            rsum[i][r] = 1.0f / v;
        }

#pragma unroll
    for (int i = 0; i < 2; ++i)
#pragma unroll
        for (int j2 = 0; j2 < 4; ++j2)
#pragma unroll
            for (int r = 0; r < 4; ++r) {
                int qrow = q0 + wq + i * 16 + quad * 4 + r;
                int hcol = nh * 64 + j2 * 16 + l15;
                Ao[(b * 2048 + qrow) * 1024 + hcol] = f2bf(oacc[i][j2][r] * rsum[i][r]);
            }
}

// ---------------------------------------------------------------------------
// 4) Output projection: BM=64 tile (512 blocks, 2/CU), dbuf gld16 pipeline.
// ---------------------------------------------------------------------------
__global__ __launch_bounds__(256) void k_proj_gemm(
    const unsigned short* __restrict__ A, const unsigned short* __restrict__ Wt,
    const float* __restrict__ bo, float* __restrict__ out) {
    __shared__ unsigned short Al[2][64 * 64];
    __shared__ unsigned short Bl[2][128 * 64];

    int n0 = blockIdx.x * 128, m0 = blockIdx.y * 64;
    int tid = threadIdx.x, lane = tid & 63, w = tid >> 6;
    int quad = lane >> 4, l15 = lane & 15;
    int wm = w >> 1, wn = w & 1;

    floatx4 acc[2][4];
#pragma unroll
    for (int i = 0; i < 2; ++i)
#pragma unroll
        for (int j = 0; j < 4; ++j) acc[i][j] = (floatx4){0.f, 0.f, 0.f, 0.f};

    int ea[2], ao[2], eb[4], bof[4];
#pragma unroll
    for (int it = 0; it < 2; ++it) {
        int e  = (it * 256 + tid) * 8;
        int rl = e >> 6;
        int c  = ((e >> 3) & 7) ^ (rl & 7);
        ea[it] = e;
        ao[it] = (m0 + rl) * 1024 + c * 8;
    }
#pragma unroll
    for (int it = 0; it < 4; ++it) {
        int e  = (it * 256 + tid) * 8;
        int rl = e >> 6;
        int c  = ((e >> 3) & 7) ^ (rl & 7);
        eb[it] = e;
        bof[it] = (n0 + rl) * 1024 + c * 8;
    }

    auto stage = [&](int buf, int k0) {
#pragma unroll
        for (int it = 0; it < 2; ++it)
            gld16(A + ao[it] + k0, (char*)Al[buf] + ea[it] * 2);
#pragma unroll
        for (int it = 0; it < 4; ++it)
            gld16(Wt + bof[it] + k0, (char*)Bl[buf] + eb[it] * 2);
    };
    auto compute = [&](int buf) {
#pragma unroll
        for (int kk = 0; kk < 2; ++kk) {
            short8 af[2], bf[4];
#pragma unroll
            for (int i = 0; i < 2; ++i) {
                int m  = wm * 32 + i * 16 + l15;
                int cp = (kk * 4 + quad) ^ (m & 7);
                af[i]  = *(const short8*)(Al[buf] + m * 64 + cp * 8);
            }
#pragma unroll
            for (int j = 0; j < 4; ++j) {
                int n  = wn * 64 + j * 16 + l15;
                int cp = (kk * 4 + quad) ^ (n & 7);
                bf[j]  = *(const short8*)(Bl[buf] + n * 64 + cp * 8);
            }
#pragma unroll
            for (int i = 0; i < 2; ++i)
#pragma unroll
                for (int j = 0; j < 4; ++j)
                    acc[i][j] = __builtin_amdgcn_mfma_f32_16x16x32_bf16(af[i], bf[j], acc[i][j], 0, 0, 0);
        }
    };

    stage(0, 0);
    __syncthreads();
    for (int kt = 0; kt < 16; kt += 2) {
        if (kt + 1 < 16) stage(1, (kt + 1) * 64);
        compute(0);
        __syncthreads();
        if (kt + 2 < 16) stage(0, (kt + 2) * 64);
        compute(1);
        __syncthreads();
    }

#pragma unroll
    for (int j = 0; j < 4; ++j) {
        int n = n0 + wn * 64 + j * 16 + l15;
        float bb = bo[n];
#pragma unroll
        for (int i = 0; i < 2; ++i) {
            int m = m0 + wm * 32 + i * 16 + quad * 4;
#pragma unroll
            for (int r = 0; r < 4; ++r)
                out[(m + r) * 1024 + n] = acc[i][j][r] + bb;
        }
    }
}

// ---------------------------------------------------------------------------
extern "C" void kernel_launch(void* const* d_in, const int* in_sizes, int n_in,
                              void* d_out, int out_size, void* d_ws, size_t ws_size,
                              hipStream_t stream) {
    (void)in_sizes; (void)n_in; (void)out_size; (void)ws_size;
    const float* q_in = (const float*)d_in[0];
    const float* s_in = (const float*)d_in[1];
    const float* mask = (const float*)d_in[2];
    const float* Wq   = (const float*)d_in[3];
    const float* bq   = (const float*)d_in[4];
    const float* Wk   = (const float*)d_in[5];
    const float* bk   = (const float*)d_in[6];
    const float* Wv   = (const float*)d_in[7];
    const float* bv   = (const float*)d_in[8];
    const float* Wo   = (const float*)d_in[9];
    const float* bo   = (const float*)d_in[10];
    float* out = (float*)d_out;

    char* ws = (char*)d_ws;
    size_t off = 0;
    auto alloc = [&](size_t bytes) {
        char* p = ws + off;
        off += (bytes + 255) & ~(size_t)255;
        return p;
    };
    unsigned short* xqp = (unsigned short*)alloc((size_t)B_ * 2050 * 1024 * 2);
    unsigned short* xsp = (unsigned short*)alloc((size_t)B_ * 2050 * 1024 * 2);
    unsigned short* Wqt = (unsigned short*)alloc((size_t)KC_ * H_ * 2);
    unsigned short* Wkt = (unsigned short*)alloc((size_t)KC_ * H_ * 2);
    unsigned short* Wvt = (unsigned short*)alloc((size_t)KC_ * H_ * 2);
    unsigned short* Wot = (unsigned short*)alloc((size_t)H_ * H_ * 2);
    unsigned short* Qb  = (unsigned short*)alloc((size_t)B_ * NH_ * S_ * D_ * 2);
    unsigned short* Kb  = (unsigned short*)alloc((size_t)B_ * NH_ * S_ * D_ * 2);
    unsigned short* Vtb = (unsigned short*)alloc((size_t)B_ * NH_ * S_ * D_ * 2);
    unsigned short* Ab  = (unsigned short*)alloc((size_t)B_ * S_ * H_ * 2);

    // pad xq (4100) + pad xs (4100) + 3x big transpose (9216) + Wo (1024)
    k_prep<<<18440, 256, 0, stream>>>(q_in, s_in, Wq, Wk, Wv, Wo,
                                      xqp, xsp, Wqt, Wkt, Wvt, Wot);
    k_conv_gemm<<<dim3(8, 32, 3), 256, 0, stream>>>(xqp, xsp, Wqt, Wkt, Wvt,
                                                    bq, bk, bv, Qb, Kb, Vtb);
    k_flash<<<dim3(16, 32), 256, 0, stream>>>(Qb, Kb, Vtb, mask, Ab);
    k_proj_gemm<<<dim3(8, 64), 256, 0, stream>>>(Ab, Wot, bo, out);
}

// Round 8
// 322.753 us; speedup vs baseline: 1.0081x; 1.0081x over previous
//
#include <hip/hip_runtime.h>
#include <stdint.h>

// Problem constants
#define B_   2
#define S_   2048      // SQ == SK
#define H_   1024
#define NH_  16
#define D_   64
#define KC_  3072      // KS*H = conv GEMM K-dim

typedef __attribute__((ext_vector_type(8))) short  short8;   // 8 x bf16 bits (4 VGPRs)
typedef __attribute__((ext_vector_type(4))) float  floatx4;  // MFMA C/D

typedef __attribute__((address_space(1))) const void gas_void;
typedef __attribute__((address_space(3))) void       las_void;

// async 16B global->LDS; LDS dest must be wave-uniform base + lane*16.
__device__ __forceinline__ void gld16(const void* g, void* l) {
    __builtin_amdgcn_global_load_lds((gas_void*)g, (las_void*)l, 16, 0, 0);
}

__device__ __forceinline__ unsigned short f2bf(float f) {
    union { float f; unsigned u; } v; v.f = f;
    unsigned r = v.u + 0x7fffu + ((v.u >> 16) & 1u);   // RNE
    return (unsigned short)(r >> 16);
}

// ---------------------------------------------------------------------------
// 1) Merged prep kernel. pad: x [B,2048,1024] f32 -> xpad [B,2050,1024] bf16,
//    zero rows 0 & 2049. transpose: W [R][C] f32 -> Wt [C][R] bf16.
// ---------------------------------------------------------------------------
__global__ __launch_bounds__(256) void k_prep(
    const float* __restrict__ qin, const float* __restrict__ sin,
    const float* __restrict__ Wq, const float* __restrict__ Wk,
    const float* __restrict__ Wv, const float* __restrict__ Wo,
    unsigned short* __restrict__ xqp, unsigned short* __restrict__ xsp,
    unsigned short* __restrict__ Wqt, unsigned short* __restrict__ Wkt,
    unsigned short* __restrict__ Wvt, unsigned short* __restrict__ Wot) {
    int bid = blockIdx.x, tid = threadIdx.x;
    if (bid < 8200) {
        const float* src = (bid < 4100) ? qin : sin;
        unsigned short* dst = (bid < 4100) ? xqp : xsp;
        int b0 = (bid < 4100) ? bid : bid - 4100;
        int vid = (b0 * 256 + tid) * 4;
        if (vid >= B_ * 2050 * 1024) return;
        int row = vid >> 10;
        int b   = (row >= 2050) ? 1 : 0;
        int r   = row - b * 2050;
        int h   = vid & 1023;
        unsigned short o0 = 0, o1 = 0, o2 = 0, o3 = 0;
        if (r != 0 && r != 2049) {
            const float4 f = *(const float4*)(src + ((b * 2048 + r - 1) << 10) + h);
            o0 = f2bf(f.x); o1 = f2bf(f.y); o2 = f2bf(f.z); o3 = f2bf(f.w);
        }
        ushort4 o; o.x = o0; o.y = o1; o.z = o2; o.w = o3;
        *(ushort4*)(dst + vid) = o;
        return;
    }
    __shared__ float t[32][33];
    const float* src; unsigned short* dst; int R, bx, by;
    int tbid = bid - 8200;
    if (tbid < 9216) {
        int w = tbid / 3072, rem = tbid - w * 3072;
        src = (w == 0) ? Wq : (w == 1 ? Wk : Wv);
        dst = (w == 0) ? Wqt : (w == 1 ? Wkt : Wvt);
        R = 3072; bx = rem & 31; by = rem >> 5;
    } else {
        int rem = tbid - 9216;
        src = Wo; dst = Wot; R = 1024; bx = rem & 31; by = rem >> 5;
    }
    const int C = 1024;
    int c0 = bx * 32, r0 = by * 32;
    int tx = tid & 31, ty = tid >> 5;
#pragma unroll
    for (int k = 0; k < 4; ++k)
        t[ty + k * 8][tx] = src[(long)(r0 + ty + k * 8) * C + c0 + tx];
    __syncthreads();
#pragma unroll
    for (int k = 0; k < 4; ++k)
        dst[(long)(c0 + ty + k * 8) * R + r0 + tx] = f2bf(t[tx][ty + k * 8]);
}

// ---------------------------------------------------------------------------
// 2) Conv-as-GEMM, shift-deduped, BK=64 (R4 version: 97 us, 0 bank conflicts).
// ---------------------------------------------------------------------------
__global__ __launch_bounds__(256) void k_conv_gemm(
    const unsigned short* __restrict__ xq, const unsigned short* __restrict__ xs,
    const unsigned short* __restrict__ Wqt, const unsigned short* __restrict__ Wkt,
    const unsigned short* __restrict__ Wvt,
    const float* __restrict__ bq, const float* __restrict__ bk, const float* __restrict__ bv,
    unsigned short* __restrict__ Qo, unsigned short* __restrict__ Ko,
    unsigned short* __restrict__ Vo) {
    int z = blockIdx.z;
    const unsigned short* X = (z == 0) ? xq : xs;
    const unsigned short* W = (z == 0) ? Wqt : (z == 1 ? Wkt : Wvt);
    const float* bias = (z == 0) ? bq : (z == 1 ? bk : bv);

    __shared__ unsigned short Al[132 * 64];        // 130 rows used
    __shared__ unsigned short Bl[3 * 128 * 64];    // [t][n][k]

    int n0 = blockIdx.x * 128, m0 = blockIdx.y * 128;
    int b = m0 >> 11;
    int tid = threadIdx.x, lane = tid & 63, w = tid >> 6;
    int quad = lane >> 4, l15 = lane & 15;
    int wm = w >> 1, wn = w & 1;

    floatx4 acc[4][4];
#pragma unroll
    for (int i = 0; i < 4; ++i)
#pragma unroll
        for (int j = 0; j < 4; ++j) acc[i][j] = (floatx4){0.f, 0.f, 0.f, 0.f};

    const unsigned short* Xbase = X + (m0 + 2 * b) * 1024;

    int eaA[4], oaA[4];
#pragma unroll
    for (int it = 0; it < 4; ++it) {
        int e  = (it * 256 + tid) * 8;
        int r  = e >> 6;
        int cp = (e >> 3) & 7;
        int c  = cp ^ (r & 7);
        eaA[it] = e;
        oaA[it] = r * 1024 + c * 8;
    }
    int eaX = 0, oaX = 0;
    if (tid < 16) {
        int e  = (1024 + tid) * 8;
        int r  = 128 + (tid >> 3);
        int cp = tid & 7;
        int c  = cp ^ (r & 7);
        eaX = e;
        oaX = r * 1024 + c * 8;
    }
    int eaB[12], oaB[12];
#pragma unroll
    for (int it = 0; it < 12; ++it) {
        int e  = (it * 256 + tid) * 8;
        int t  = e >> 13;
        int er = e & 8191;
        int rl = er >> 6;
        int cp = (er >> 3) & 7;
        int c  = cp ^ (rl & 7);
        eaB[it] = e;
        oaB[it] = (n0 + rl) * KC_ + t * 1024 + c * 8;
    }

    for (int kt = 0; kt < 16; ++kt) {
        int k0 = kt * 64;
#pragma unroll
        for (int it = 0; it < 4; ++it)
            gld16(Xbase + oaA[it] + k0, (char*)Al + eaA[it] * 2);
        if (tid < 16)
            gld16(Xbase + oaX + k0, (char*)Al + eaX * 2);
#pragma unroll
        for (int it = 0; it < 12; ++it)
            gld16(W + oaB[it] + k0, (char*)Bl + eaB[it] * 2);
        __syncthreads();

#pragma unroll
        for (int t = 0; t < 3; ++t) {
#pragma unroll
            for (int kk = 0; kk < 2; ++kk) {
                short8 af[4], bf[4];
#pragma unroll
                for (int i = 0; i < 4; ++i) {
                    int r  = wm * 64 + i * 16 + l15 + t;
                    int cp = (kk * 4 + quad) ^ (r & 7);
                    af[i]  = *(const short8*)(Al + r * 64 + cp * 8);
                }
#pragma unroll
                for (int j = 0; j < 4; ++j) {
                    int n  = wn * 64 + j * 16 + l15;
                    int cp = (kk * 4 + quad) ^ (n & 7);
                    bf[j]  = *(const short8*)(Bl + t * 8192 + n * 64 + cp * 8);
                }
#pragma unroll
                for (int i = 0; i < 4; ++i)
#pragma unroll
                    for (int j = 0; j < 4; ++j)
                        acc[i][j] = __builtin_amdgcn_mfma_f32_16x16x32_bf16(af[i], bf[j], acc[i][j], 0, 0, 0);
            }
        }
        __syncthreads();
    }

#pragma unroll
    for (int j = 0; j < 4; ++j) {
        int n = n0 + wn * 64 + j * 16 + l15;
        float bb = bias[n];
        int nh = n >> 6, d = n & 63;
#pragma unroll
        for (int i = 0; i < 4; ++i) {
            int srow = (m0 & 2047) + wm * 64 + i * 16 + quad * 4;
#pragma unroll
            for (int r = 0; r < 4; ++r) {
                float v = acc[i][j][r] + bb;
                int s = srow + r;
                if (z == 0)
                    Qo[((b * NH_ + nh) * 2048 + s) * 64 + d] = f2bf(v * 0.125f);
                else if (z == 1)
                    Ko[((b * NH_ + nh) * 2048 + s) * 64 + d] = f2bf(v);
                else
                    Vo[((b * NH_ + nh) * 64 + d) * 2048 + s] = f2bf(v);
            }
        }
    }
}

// ---------------------------------------------------------------------------
// 3) Flash attention, transposed-S variant.
//    S^T = mfma(A=K, B=Q) -> lane holds 4 contiguous keys of one q-column ->
//    P stored q-major with packed b64 writes. PV: O^T = mfma(A=V^T, B=P^T).
//    R7 FAILURE FIX: the P-write -> PV-read handoff now has an explicit
//    __syncthreads(). R7 relied on in-wave LDS ordering for the packed
//    b64-write/b128-read pair and showed the "first launch right, later
//    launches self-consistently wrong" signature of a read beating its
//    covering write (stale-LDS fixed point). Barrier makes it airtight.
// ---------------------------------------------------------------------------
__global__ __launch_bounds__(256) void k_flash(
    const unsigned short* __restrict__ Q, const unsigned short* __restrict__ K,
    const unsigned short* __restrict__ Vt, const float* __restrict__ mask,
    unsigned short* __restrict__ Ao) {
    __shared__ unsigned short Ul[128 * 136];   // union: K-tile 128x64 | P[q][key] pitch 136
    __shared__ unsigned short Vl[64 * 128];    // V^T tile [d][key]

    int tid = threadIdx.x, w = tid >> 6, lane = tid & 63;
    int quad = lane >> 4, l15 = lane & 15;
    int bh = blockIdx.y;
    int b = bh >> 4, nh = bh & 15;
    int q0 = blockIdx.x * 128, wq = w * 32;

    // Q fragments as B-operand: lane n=q=l15 holds k=d=quad*8+jj
    short8 qf[2][2];
#pragma unroll
    for (int i = 0; i < 2; ++i)
#pragma unroll
        for (int kk = 0; kk < 2; ++kk)
            qf[i][kk] = *(const short8*)(Q + ((bh * 2048 + q0 + wq + i * 16 + l15) << 6) + kk * 32 + quad * 8);

    floatx4 oacc[2][4];
    float rsum[2] = {0.f, 0.f};
#pragma unroll
    for (int i = 0; i < 2; ++i)
#pragma unroll
        for (int m = 0; m < 4; ++m) oacc[i][m] = (floatx4){0.f, 0.f, 0.f, 0.f};
    const float* maskb = mask + b * S_;

    for (int kt = 0; kt < 16; ++kt) {
        int k0 = kt * 128;
#pragma unroll
        for (int it = 0; it < 4; ++it) {
            int e  = (it * 256 + tid) * 8;
            int kl = e >> 6;
            int c  = ((e >> 3) & 7) ^ (kl & 7);
            gld16(K + (bh * 2048 + k0 + kl) * 64 + c * 8, (char*)Ul + e * 2);
            int dl = e >> 7;
            int cp = (e >> 3) & 15;
            int c2 = (cp & 8) | ((cp ^ dl) & 7);
            gld16(Vt + (bh * 64 + dl) * 2048 + k0 + c2 * 8, (char*)Vl + e * 2);
        }
        __syncthreads();

        // S^T = K Q^T : D[key][q]  (wave: 128 keys x its 32 q)
        floatx4 sacc[2][8];
#pragma unroll
        for (int i = 0; i < 2; ++i)
#pragma unroll
            for (int jb = 0; jb < 8; ++jb) sacc[i][jb] = (floatx4){0.f, 0.f, 0.f, 0.f};
#pragma unroll
        for (int jb = 0; jb < 8; ++jb) {
            int kl = jb * 16 + l15;
            int cp0 = quad ^ (kl & 7);
            short8 af0 = *(const short8*)(Ul + kl * 64 + cp0 * 8);
            int cp1 = (4 + quad) ^ (kl & 7);
            short8 af1 = *(const short8*)(Ul + kl * 64 + cp1 * 8);
#pragma unroll
            for (int i = 0; i < 2; ++i) {
                sacc[i][jb] = __builtin_amdgcn_mfma_f32_16x16x32_bf16(af0, qf[i][0], sacc[i][jb], 0, 0, 0);
                sacc[i][jb] = __builtin_amdgcn_mfma_f32_16x16x32_bf16(af1, qf[i][1], sacc[i][jb], 0, 0, 0);
            }
        }
        __syncthreads();   // all waves done reading K-tile before P overwrites Ul

        // P = exp(S^T + mask*-1e9), packed b64 stores into P[q][key]
#pragma unroll
        for (int i = 0; i < 2; ++i) {
            int qrow = wq + i * 16 + l15;
#pragma unroll
            for (int jb = 0; jb < 8; ++jb) {
                const float4 mv4 = *(const float4*)(maskb + k0 + jb * 16 + quad * 4);
                float p0 = __expf(sacc[i][jb][0] + mv4.x * (-1e9f));
                float p1 = __expf(sacc[i][jb][1] + mv4.y * (-1e9f));
                float p2 = __expf(sacc[i][jb][2] + mv4.z * (-1e9f));
                float p3 = __expf(sacc[i][jb][3] + mv4.w * (-1e9f));
                rsum[i] += (p0 + p1) + (p2 + p3);
                ushort4 pk;
                pk.x = f2bf(p0); pk.y = f2bf(p1); pk.z = f2bf(p2); pk.w = f2bf(p3);
                *(ushort4*)(Ul + qrow * 136 + jb * 16 + quad * 4) = pk;
            }
        }
        __syncthreads();   // P writes fully visible before PV reads (R7 fix)

        // O^T += V^T P^T : D[d][q]
#pragma unroll
        for (int kk = 0; kk < 4; ++kk) {
            short8 av[4], bp[2];
#pragma unroll
            for (int m = 0; m < 4; ++m) {
                int dl = m * 16 + l15;
                int c  = kk * 4 + quad;
                int cp = (c & 8) | ((c ^ dl) & 7);
                av[m]  = *(const short8*)(Vl + dl * 128 + cp * 8);
            }
#pragma unroll
            for (int i = 0; i < 2; ++i)
                bp[i] = *(const short8*)(Ul + (wq + i * 16 + l15) * 136 + kk * 32 + quad * 8);
#pragma unroll
            for (int i = 0; i < 2; ++i)
#pragma unroll
                for (int m = 0; m < 4; ++m)
                    oacc[i][m] = __builtin_amdgcn_mfma_f32_16x16x32_bf16(av[m], bp[i], oacc[i][m], 0, 0, 0);
        }
        __syncthreads();   // before next iter restages Ul/Vl
    }

    // normalize + write: lane holds (d = m*16+quad*4+r, q = wq+i*16+l15)
#pragma unroll
    for (int i = 0; i < 2; ++i) {
        float v = rsum[i];
        v += __shfl_xor(v, 16);
        v += __shfl_xor(v, 32);
        float inv = 1.0f / v;
        int qrow = q0 + wq + i * 16 + l15;
#pragma unroll
        for (int m = 0; m < 4; ++m) {
            ushort4 o;
            o.x = f2bf(oacc[i][m][0] * inv);
            o.y = f2bf(oacc[i][m][1] * inv);
            o.z = f2bf(oacc[i][m][2] * inv);
            o.w = f2bf(oacc[i][m][3] * inv);
            *(ushort4*)(Ao + (b * 2048 + qrow) * 1024 + nh * 64 + m * 16 + quad * 4) = o;
        }
    }
}

// ---------------------------------------------------------------------------
// 4) Output projection: BM=64 tile (512 blocks, 2/CU), dbuf gld16 pipeline.
// ---------------------------------------------------------------------------
__global__ __launch_bounds__(256) void k_proj_gemm(
    const unsigned short* __restrict__ A, const unsigned short* __restrict__ Wt,
    const float* __restrict__ bo, float* __restrict__ out) {
    __shared__ unsigned short Al[2][64 * 64];
    __shared__ unsigned short Bl[2][128 * 64];

    int n0 = blockIdx.x * 128, m0 = blockIdx.y * 64;
    int tid = threadIdx.x, lane = tid & 63, w = tid >> 6;
    int quad = lane >> 4, l15 = lane & 15;
    int wm = w >> 1, wn = w & 1;

    floatx4 acc[2][4];
#pragma unroll
    for (int i = 0; i < 2; ++i)
#pragma unroll
        for (int j = 0; j < 4; ++j) acc[i][j] = (floatx4){0.f, 0.f, 0.f, 0.f};

    int ea[2], ao[2], eb[4], bof[4];
#pragma unroll
    for (int it = 0; it < 2; ++it) {
        int e  = (it * 256 + tid) * 8;
        int rl = e >> 6;
        int c  = ((e >> 3) & 7) ^ (rl & 7);
        ea[it] = e;
        ao[it] = (m0 + rl) * 1024 + c * 8;
    }
#pragma unroll
    for (int it = 0; it < 4; ++it) {
        int e  = (it * 256 + tid) * 8;
        int rl = e >> 6;
        int c  = ((e >> 3) & 7) ^ (rl & 7);
        eb[it] = e;
        bof[it] = (n0 + rl) * 1024 + c * 8;
    }

    auto stage = [&](int buf, int k0) {
#pragma unroll
        for (int it = 0; it < 2; ++it)
            gld16(A + ao[it] + k0, (char*)Al[buf] + ea[it] * 2);
#pragma unroll
        for (int it = 0; it < 4; ++it)
            gld16(Wt + bof[it] + k0, (char*)Bl[buf] + eb[it] * 2);
    };
    auto compute = [&](int buf) {
#pragma unroll
        for (int kk = 0; kk < 2; ++kk) {
            short8 af[2], bf[4];
#pragma unroll
            for (int i = 0; i < 2; ++i) {
                int m  = wm * 32 + i * 16 + l15;
                int cp = (kk * 4 + quad) ^ (m & 7);
                af[i]  = *(const short8*)(Al[buf] + m * 64 + cp * 8);
            }
#pragma unroll
            for (int j = 0; j < 4; ++j) {
                int n  = wn * 64 + j * 16 + l15;
                int cp = (kk * 4 + quad) ^ (n & 7);
                bf[j]  = *(const short8*)(Bl[buf] + n * 64 + cp * 8);
            }
#pragma unroll
            for (int i = 0; i < 2; ++i)
#pragma unroll
                for (int j = 0; j < 4; ++j)
                    acc[i][j] = __builtin_amdgcn_mfma_f32_16x16x32_bf16(af[i], bf[j], acc[i][j], 0, 0, 0);
        }
    };

    stage(0, 0);
    __syncthreads();
    for (int kt = 0; kt < 16; kt += 2) {
        if (kt + 1 < 16) stage(1, (kt + 1) * 64);
        compute(0);
        __syncthreads();
        if (kt + 2 < 16) stage(0, (kt + 2) * 64);
        compute(1);
        __syncthreads();
    }

#pragma unroll
    for (int j = 0; j < 4; ++j) {
        int n = n0 + wn * 64 + j * 16 + l15;
        float bb = bo[n];
#pragma unroll
        for (int i = 0; i < 2; ++i) {
            int m = m0 + wm * 32 + i * 16 + quad * 4;
#pragma unroll
            for (int r = 0; r < 4; ++r)
                out[(m + r) * 1024 + n] = acc[i][j][r] + bb;
        }
    }
}

// ---------------------------------------------------------------------------
extern "C" void kernel_launch(void* const* d_in, const int* in_sizes, int n_in,
                              void* d_out, int out_size, void* d_ws, size_t ws_size,
                              hipStream_t stream) {
    (void)in_sizes; (void)n_in; (void)out_size; (void)ws_size;
    const float* q_in = (const float*)d_in[0];
    const float* s_in = (const float*)d_in[1];
    const float* mask = (const float*)d_in[2];
    const float* Wq   = (const float*)d_in[3];
    const float* bq   = (const float*)d_in[4];
    const float* Wk   = (const float*)d_in[5];
    const float* bk   = (const float*)d_in[6];
    const float* Wv   = (const float*)d_in[7];
    const float* bv   = (const float*)d_in[8];
    const float* Wo   = (const float*)d_in[9];
    const float* bo   = (const float*)d_in[10];
    float* out = (float*)d_out;

    char* ws = (char*)d_ws;
    size_t off = 0;
    auto alloc = [&](size_t bytes) {
        char* p = ws + off;
        off += (bytes + 255) & ~(size_t)255;
        return p;
    };
    unsigned short* xqp = (unsigned short*)alloc((size_t)B_ * 2050 * 1024 * 2);
    unsigned short* xsp = (unsigned short*)alloc((size_t)B_ * 2050 * 1024 * 2);
    unsigned short* Wqt = (unsigned short*)alloc((size_t)KC_ * H_ * 2);
    unsigned short* Wkt = (unsigned short*)alloc((size_t)KC_ * H_ * 2);
    unsigned short* Wvt = (unsigned short*)alloc((size_t)KC_ * H_ * 2);
    unsigned short* Wot = (unsigned short*)alloc((size_t)H_ * H_ * 2);
    unsigned short* Qb  = (unsigned short*)alloc((size_t)B_ * NH_ * S_ * D_ * 2);
    unsigned short* Kb  = (unsigned short*)alloc((size_t)B_ * NH_ * S_ * D_ * 2);
    unsigned short* Vtb = (unsigned short*)alloc((size_t)B_ * NH_ * S_ * D_ * 2);
    unsigned short* Ab  = (unsigned short*)alloc((size_t)B_ * S_ * H_ * 2);

    k_prep<<<18440, 256, 0, stream>>>(q_in, s_in, Wq, Wk, Wv, Wo,
                                      xqp, xsp, Wqt, Wkt, Wvt, Wot);
    k_conv_gemm<<<dim3(8, 32, 3), 256, 0, stream>>>(xqp, xsp, Wqt, Wkt, Wvt,
                                                    bq, bk, bv, Qb, Kb, Vtb);
    k_flash<<<dim3(16, 32), 256, 0, stream>>>(Qb, Kb, Vtb, mask, Ab);
    k_proj_gemm<<<dim3(8, 64), 256, 0, stream>>>(Ab, Wot, bo, out);
}